// Round 7
// baseline (487.486 us; speedup 1.0000x reference)
//
#include <hip/hip_runtime.h>

#define CDIM 64

typedef __attribute__((ext_vector_type(8))) short bf16x8;
typedef __attribute__((ext_vector_type(4))) float f32x4;

// round-to-nearest-even fp32 -> bf16 (as short)
__device__ __forceinline__ short bf16r(float f) {
    unsigned a = __float_as_uint(f);
    a = (a + 0x7fffu + ((a >> 16) & 1u)) >> 16;
    return (short)a;
}
// pack two fp32 as bf16 pair: lo bits[15:0], hi bits[31:16]
__device__ __forceinline__ unsigned bfpack(float lo, float hi) {
    unsigned a = __float_as_uint(lo);
    a = (a + 0x7fffu + ((a >> 16) & 1u)) >> 16;
    unsigned b = __float_as_uint(hi);
    b = (b + 0x7fffu + ((b >> 16) & 1u)) & 0xffff0000u;
    return a | b;
}

// --- MFMA 3-GEMM: block = 64 nodes (4 waves x 16); W^T staged in LDS bf16 ---
// m92-verified layout: A[m=lane&15][k=quad*8+j]; B from Bt[n=lane&15][k=quad*8+j];
// D: col=lane&15 (n), row=quad*4+reg (m).
__global__ __launch_bounds__(256) void k_gemm3(const float* __restrict__ x,
                                               const float* __restrict__ w0,
                                               const float* __restrict__ w1,
                                               const float* __restrict__ root,
                                               const float* __restrict__ bias,
                                               unsigned* __restrict__ h01,
                                               float* __restrict__ lin,
                                               int n_nodes) {
    // Wt[mat][n][k], k padded 64->72 so rows are 144 B (16B-aligned b128 reads)
    __shared__ __align__(16) short wt[3][64][72];
    const float* ws[3] = {w0, w1, root};
#pragma unroll
    for (int m = 0; m < 3; ++m) {
        const float* w = ws[m];
        for (int i = threadIdx.x; i < 4096; i += 256) {
            int k = i >> 6, n = i & 63;      // w row-major [k][n]
            wt[m][n][k] = bf16r(w[i]);
        }
    }
    __syncthreads();

    int wave = threadIdx.x >> 6;
    int lane = threadIdx.x & 63;
    int quad = lane >> 4;
    int m16 = lane & 15;
    int node0 = blockIdx.x * 64 + wave * 16;

    // A-frags: 16 nodes x 64 k, two k-halves
    bf16x8 afrag[2];
    int arow = node0 + m16;
    bool rowok = arow < n_nodes;
    const float* xp = x + (size_t)arow * CDIM + quad * 8;
#pragma unroll
    for (int kf = 0; kf < 2; ++kf) {
        float4 lo = {0.f, 0.f, 0.f, 0.f}, hi = {0.f, 0.f, 0.f, 0.f};
        if (rowok) {
            lo = *(const float4*)(xp + kf * 32);
            hi = *(const float4*)(xp + kf * 32 + 4);
        }
        bf16x8 a;
        a[0] = bf16r(lo.x); a[1] = bf16r(lo.y); a[2] = bf16r(lo.z); a[3] = bf16r(lo.w);
        a[4] = bf16r(hi.x); a[5] = bf16r(hi.y); a[6] = bf16r(hi.z); a[7] = bf16r(hi.w);
        afrag[kf] = a;
    }

#pragma unroll
    for (int nt = 0; nt < 4; ++nt) {
        f32x4 acc0 = {0.f, 0.f, 0.f, 0.f};
        f32x4 acc1 = {0.f, 0.f, 0.f, 0.f};
        f32x4 accR = {0.f, 0.f, 0.f, 0.f};
#pragma unroll
        for (int kf = 0; kf < 2; ++kf) {
            bf16x8 b0 = *(const bf16x8*)&wt[0][nt * 16 + m16][kf * 32 + quad * 8];
            bf16x8 b1 = *(const bf16x8*)&wt[1][nt * 16 + m16][kf * 32 + quad * 8];
            bf16x8 bR = *(const bf16x8*)&wt[2][nt * 16 + m16][kf * 32 + quad * 8];
            acc0 = __builtin_amdgcn_mfma_f32_16x16x32_bf16(afrag[kf], b0, acc0, 0, 0, 0);
            acc1 = __builtin_amdgcn_mfma_f32_16x16x32_bf16(afrag[kf], b1, acc1, 0, 0, 0);
            accR = __builtin_amdgcn_mfma_f32_16x16x32_bf16(afrag[kf], bR, accR, 0, 0, 0);
        }
        float bcol = bias[nt * 16 + m16];
#pragma unroll
        for (int r = 0; r < 4; ++r) {
            int node = node0 + quad * 4 + r;
            if (node < n_nodes) {
                size_t off = (size_t)node * CDIM + nt * 16 + m16;
                h01[off] = bfpack(acc0[r], acc1[r]);
                lin[off] = accR[r] + bcol;
            }
        }
    }
}

// --- zero-fill ---
__global__ __launch_bounds__(256) void k_zero(int* __restrict__ p, size_t n) {
    size_t t = (size_t)blockIdx.x * 256 + threadIdx.x;
    size_t stride = (size_t)gridDim.x * 256;
    for (size_t i = t; i < n; i += stride) p[i] = 0;
}

// --- histogram of dst (nt load: single-use stream) ---
__global__ __launch_bounds__(256) void k_hist(const int* __restrict__ dst,
                                              int* __restrict__ cnt, int n_edges) {
    int e = blockIdx.x * 256 + threadIdx.x;
    if (e >= n_edges) return;
    int d = __builtin_nontemporal_load(dst + e);
    atomicAdd(&cnt[d], 1);
}

// ===== two-level scan: 1024 elements per block =====
#define SCAN_B 1024

__global__ __launch_bounds__(256) void k_scan1(const int* __restrict__ cnt,
                                               int* __restrict__ blk_sum, int n) {
    __shared__ int sm[256];
    int tid = threadIdx.x;
    int base = blockIdx.x * SCAN_B + tid * 4;
    int s = 0;
#pragma unroll
    for (int i = 0; i < 4; ++i) s += (base + i < n) ? cnt[base + i] : 0;
    sm[tid] = s;
    __syncthreads();
    for (int off = 128; off > 0; off >>= 1) {
        if (tid < off) sm[tid] += sm[tid + off];
        __syncthreads();
    }
    if (tid == 0) blk_sum[blockIdx.x] = sm[0];
}

__global__ __launch_bounds__(256) void k_scan2(int* __restrict__ blk_sum,
                                               int* __restrict__ row_start,
                                               int nb, int n) {
    __shared__ int sm[256];
    int tid = threadIdx.x;
    int v = (tid < nb) ? blk_sum[tid] : 0;
    sm[tid] = v;
    __syncthreads();
    for (int off = 1; off < 256; off <<= 1) {
        int t = (tid >= off) ? sm[tid - off] : 0;
        __syncthreads();
        sm[tid] += t;
        __syncthreads();
    }
    if (tid < nb) blk_sum[tid] = sm[tid] - v;  // exclusive
    if (tid == 255) row_start[n] = sm[255];    // grand total
}

__global__ __launch_bounds__(256) void k_scan3(const int* __restrict__ cnt,
                                               const int* __restrict__ blk_off,
                                               int* __restrict__ row_start,
                                               int* __restrict__ cursor, int n) {
    __shared__ int sm[256];
    int tid = threadIdx.x;
    int base = blockIdx.x * SCAN_B + tid * 4;
    int v[4];
    int s = 0;
#pragma unroll
    for (int i = 0; i < 4; ++i) {
        v[i] = (base + i < n) ? cnt[base + i] : 0;
        s += v[i];
    }
    sm[tid] = s;
    __syncthreads();
    for (int off = 1; off < 256; off <<= 1) {
        int t = (tid >= off) ? sm[tid - off] : 0;
        __syncthreads();
        sm[tid] += t;
        __syncthreads();
    }
    int run = sm[tid] - s + blk_off[blockIdx.x];
#pragma unroll
    for (int i = 0; i < 4; ++i) {
        if (base + i < n) {
            row_start[base + i] = run;
            cursor[base + i] = run;
        }
        run += v[i];
    }
}

// --- bucketed scatter: bucket = blockIdx&7 (XCD round-robin heuristic) ---
// nt loads on src/dst/u keep the streaming reads out of L2 so the bucket's
// ~1.6 MB em write window stays resident and lines fill before writeback.
__global__ __launch_bounds__(256) void k_scatter(const int* __restrict__ src,
                                                 const int* __restrict__ dst,
                                                 const float* __restrict__ u,
                                                 int* __restrict__ cursor,
                                                 int2* __restrict__ em,
                                                 int n_edges, int nodes_per_bucket) {
    int bucket = blockIdx.x & 7;
    int chunk = blockIdx.x >> 3;
    int nchunks = gridDim.x >> 3;
    int per = (n_edges + nchunks - 1) / nchunks;
    int e0 = chunk * per;
    int e1 = min(e0 + per, n_edges);
    int lo = bucket * nodes_per_bucket;
    int hi = lo + nodes_per_bucket;
    for (int e = e0 + threadIdx.x; e < e1; e += 256) {
        int d = __builtin_nontemporal_load(dst + e);
        if (d >= lo && d < hi) {
            int s = __builtin_nontemporal_load(src + e);
            float uu = __builtin_nontemporal_load(u + e);
            int p = atomicAdd(&cursor[d], 1);
            em[p] = make_int2(s, __float_as_int(uu));
        }
    }
}

// --- aggregate: one wave per node, lane = channel; packed bf16 h01 ---
// em read via nt loads (single-use stream) to keep L2 for h01 gather reuse.
__global__ __launch_bounds__(256) void k_agg(const unsigned* __restrict__ h01,
                                             const long long* __restrict__ em,
                                             const int* __restrict__ row_start,
                                             const float* __restrict__ lin,
                                             float* __restrict__ out, int n_nodes) {
    int wave = threadIdx.x >> 6;
    int lane = threadIdx.x & 63;
    int n = blockIdx.x * 4 + wave;
    if (n >= n_nodes) return;
    int start = row_start[n];
    int end = row_start[n + 1];
    float acc = 0.0f;
    int j = start;
    for (; j + 8 <= end; j += 8) {
        long long e[8];
        unsigned v[8];
#pragma unroll
        for (int i = 0; i < 8; ++i) e[i] = __builtin_nontemporal_load(em + j + i);
#pragma unroll
        for (int i = 0; i < 8; ++i) {
            int s = (int)(e[i] & 0xffffffffLL);
            v[i] = h01[(size_t)s * CDIM + lane];
        }
#pragma unroll
        for (int i = 0; i < 8; ++i) {
            float a = __uint_as_float(v[i] << 16);
            float b = __uint_as_float(v[i] & 0xffff0000u);
            float uu = __int_as_float((int)(e[i] >> 32));
            acc += a + uu * (b - a);   // (1-u)h0 + u h1
        }
    }
    for (; j < end; ++j) {
        long long e = __builtin_nontemporal_load(em + j);
        int s = (int)(e & 0xffffffffLL);
        unsigned v = h01[(size_t)s * CDIM + lane];
        float a = __uint_as_float(v << 16), b = __uint_as_float(v & 0xffff0000u);
        acc += a + __int_as_float((int)(e >> 32)) * (b - a);
    }
    float d = fmaxf((float)(end - start), 1.0f);
    size_t o = (size_t)n * CDIM + lane;
    out[o] = acc / d + lin[o];
}

extern "C" void kernel_launch(void* const* d_in, const int* in_sizes, int n_in,
                              void* d_out, int out_size, void* d_ws, size_t ws_size,
                              hipStream_t stream) {
    const float* x = (const float*)d_in[0];
    const int* edge_index = (const int*)d_in[1];
    const float* edge_attr = (const float*)d_in[2];
    const float* w1 = (const float*)d_in[3];
    const float* root1 = (const float*)d_in[4];
    const float* b1 = (const float*)d_in[5];
    const float* w2 = (const float*)d_in[6];
    const float* root2 = (const float*)d_in[7];
    const float* b2 = (const float*)d_in[8];

    int n_nodes = in_sizes[0] / CDIM;
    int n_edges = in_sizes[2];
    const int* src = edge_index;
    const int* dst = edge_index + n_edges;

    size_t F = (size_t)n_nodes * CDIM;
    unsigned* h01 = (unsigned*)d_ws;            // F u32 (bf16 pair)
    float* lin = (float*)(h01 + F);             // F floats
    int2* em = (int2*)(lin + F);                // E int2 (src, u)
    int* cnt = (int*)(em + n_edges);
    int* row_start = cnt + n_nodes;             // n+1
    int* cursor = row_start + n_nodes + 1;
    int* blk_sum = cursor + n_nodes;
    float* out = (float*)d_out;

    int gB = (n_nodes + 63) / 64;               // 64 nodes per gemm block
    int gE = (n_edges + 255) / 256;
    int gA = (n_nodes + 3) / 4;
    int nb = (n_nodes + SCAN_B - 1) / SCAN_B;   // 98 for 100k, fits k_scan2's 256
    int npb = (n_nodes + 7) / 8;                // nodes per scatter bucket

    // ---- build dst-CSR (shared by both layers) ----
    k_zero<<<256, 256, 0, stream>>>(cnt, (size_t)n_nodes);
    k_hist<<<gE, 256, 0, stream>>>(dst, cnt, n_edges);
    k_scan1<<<nb, 256, 0, stream>>>(cnt, blk_sum, n_nodes);
    k_scan2<<<1, 256, 0, stream>>>(blk_sum, row_start, nb, n_nodes);
    k_scan3<<<nb, 256, 0, stream>>>(cnt, blk_sum, row_start, cursor, n_nodes);
    k_scatter<<<8 * 128, 256, 0, stream>>>(src, dst, edge_attr, cursor, em, n_edges, npb);

    // ---- layer 1 ----
    k_gemm3<<<gB, 256, 0, stream>>>(x, w1, w1 + CDIM * CDIM, root1, b1, h01, lin, n_nodes);
    k_agg<<<gA, 256, 0, stream>>>(h01, (const long long*)em, row_start, lin, lin, n_nodes);

    // ---- layer 2 ----
    k_gemm3<<<gB, 256, 0, stream>>>(lin, w2, w2 + CDIM * CDIM, root2, b2, h01, out, n_nodes);
    k_agg<<<gA, 256, 0, stream>>>(h01, (const long long*)em, row_start, out, out, n_nodes);
}

// Round 8
// 453.593 us; speedup vs baseline: 1.0747x; 1.0747x over previous
//
#include <hip/hip_runtime.h>

#define CDIM 64

typedef __attribute__((ext_vector_type(8))) short bf16x8;
typedef __attribute__((ext_vector_type(4))) float f32x4;

// round-to-nearest-even fp32 -> bf16 (as short)
__device__ __forceinline__ short bf16r(float f) {
    unsigned a = __float_as_uint(f);
    a = (a + 0x7fffu + ((a >> 16) & 1u)) >> 16;
    return (short)a;
}
// pack two fp32 as bf16 pair: lo bits[15:0], hi bits[31:16]
__device__ __forceinline__ unsigned bfpack(float lo, float hi) {
    unsigned a = __float_as_uint(lo);
    a = (a + 0x7fffu + ((a >> 16) & 1u)) >> 16;
    unsigned b = __float_as_uint(hi);
    b = (b + 0x7fffu + ((b >> 16) & 1u)) & 0xffff0000u;
    return a | b;
}

// --- MFMA 3-GEMM: block = 64 nodes (4 waves x 16); W^T staged in LDS bf16 ---
__global__ __launch_bounds__(256) void k_gemm3(const float* __restrict__ x,
                                               const float* __restrict__ w0,
                                               const float* __restrict__ w1,
                                               const float* __restrict__ root,
                                               const float* __restrict__ bias,
                                               unsigned* __restrict__ h01,
                                               float* __restrict__ lin,
                                               int n_nodes) {
    // Wt[mat][n][k], k padded 64->72 so rows are 144 B (16B-aligned b128 reads)
    __shared__ __align__(16) short wt[3][64][72];
    const float* ws[3] = {w0, w1, root};
#pragma unroll
    for (int m = 0; m < 3; ++m) {
        const float* w = ws[m];
        for (int i = threadIdx.x; i < 4096; i += 256) {
            int k = i >> 6, n = i & 63;      // w row-major [k][n]
            wt[m][n][k] = bf16r(w[i]);
        }
    }
    __syncthreads();

    int wave = threadIdx.x >> 6;
    int lane = threadIdx.x & 63;
    int quad = lane >> 4;
    int m16 = lane & 15;
    int node0 = blockIdx.x * 64 + wave * 16;

    bf16x8 afrag[2];
    int arow = node0 + m16;
    bool rowok = arow < n_nodes;
    const float* xp = x + (size_t)arow * CDIM + quad * 8;
#pragma unroll
    for (int kf = 0; kf < 2; ++kf) {
        float4 lo = {0.f, 0.f, 0.f, 0.f}, hi = {0.f, 0.f, 0.f, 0.f};
        if (rowok) {
            lo = *(const float4*)(xp + kf * 32);
            hi = *(const float4*)(xp + kf * 32 + 4);
        }
        bf16x8 a;
        a[0] = bf16r(lo.x); a[1] = bf16r(lo.y); a[2] = bf16r(lo.z); a[3] = bf16r(lo.w);
        a[4] = bf16r(hi.x); a[5] = bf16r(hi.y); a[6] = bf16r(hi.z); a[7] = bf16r(hi.w);
        afrag[kf] = a;
    }

#pragma unroll
    for (int nt = 0; nt < 4; ++nt) {
        f32x4 acc0 = {0.f, 0.f, 0.f, 0.f};
        f32x4 acc1 = {0.f, 0.f, 0.f, 0.f};
        f32x4 accR = {0.f, 0.f, 0.f, 0.f};
#pragma unroll
        for (int kf = 0; kf < 2; ++kf) {
            bf16x8 b0 = *(const bf16x8*)&wt[0][nt * 16 + m16][kf * 32 + quad * 8];
            bf16x8 b1 = *(const bf16x8*)&wt[1][nt * 16 + m16][kf * 32 + quad * 8];
            bf16x8 bR = *(const bf16x8*)&wt[2][nt * 16 + m16][kf * 32 + quad * 8];
            acc0 = __builtin_amdgcn_mfma_f32_16x16x32_bf16(afrag[kf], b0, acc0, 0, 0, 0);
            acc1 = __builtin_amdgcn_mfma_f32_16x16x32_bf16(afrag[kf], b1, acc1, 0, 0, 0);
            accR = __builtin_amdgcn_mfma_f32_16x16x32_bf16(afrag[kf], bR, accR, 0, 0, 0);
        }
        float bcol = bias[nt * 16 + m16];
#pragma unroll
        for (int r = 0; r < 4; ++r) {
            int node = node0 + quad * 4 + r;
            if (node < n_nodes) {
                size_t off = (size_t)node * CDIM + nt * 16 + m16;
                h01[off] = bfpack(acc0[r], acc1[r]);
                lin[off] = accR[r] + bcol;
            }
        }
    }
}

// --- zero-fill ---
__global__ __launch_bounds__(256) void k_zero(int* __restrict__ p, size_t n) {
    size_t t = (size_t)blockIdx.x * 256 + threadIdx.x;
    size_t stride = (size_t)gridDim.x * 256;
    for (size_t i = t; i < n; i += stride) p[i] = 0;
}

// --- histogram of dst (regular load: warms L3 for scatter's 8x re-read) ---
__global__ __launch_bounds__(256) void k_hist(const int* __restrict__ dst,
                                              int* __restrict__ cnt, int n_edges) {
    int e = blockIdx.x * 256 + threadIdx.x;
    if (e >= n_edges) return;
    atomicAdd(&cnt[dst[e]], 1);
}

// ===== two-level scan: 1024 elements per block =====
#define SCAN_B 1024

__global__ __launch_bounds__(256) void k_scan1(const int* __restrict__ cnt,
                                               int* __restrict__ blk_sum, int n) {
    __shared__ int sm[256];
    int tid = threadIdx.x;
    int base = blockIdx.x * SCAN_B + tid * 4;
    int s = 0;
#pragma unroll
    for (int i = 0; i < 4; ++i) s += (base + i < n) ? cnt[base + i] : 0;
    sm[tid] = s;
    __syncthreads();
    for (int off = 128; off > 0; off >>= 1) {
        if (tid < off) sm[tid] += sm[tid + off];
        __syncthreads();
    }
    if (tid == 0) blk_sum[blockIdx.x] = sm[0];
}

__global__ __launch_bounds__(256) void k_scan2(int* __restrict__ blk_sum,
                                               int* __restrict__ row_start,
                                               int nb, int n) {
    __shared__ int sm[256];
    int tid = threadIdx.x;
    int v = (tid < nb) ? blk_sum[tid] : 0;
    sm[tid] = v;
    __syncthreads();
    for (int off = 1; off < 256; off <<= 1) {
        int t = (tid >= off) ? sm[tid - off] : 0;
        __syncthreads();
        sm[tid] += t;
        __syncthreads();
    }
    if (tid < nb) blk_sum[tid] = sm[tid] - v;  // exclusive
    if (tid == 255) row_start[n] = sm[255];    // grand total
}

__global__ __launch_bounds__(256) void k_scan3(const int* __restrict__ cnt,
                                               const int* __restrict__ blk_off,
                                               int* __restrict__ row_start,
                                               int* __restrict__ cursor, int n) {
    __shared__ int sm[256];
    int tid = threadIdx.x;
    int base = blockIdx.x * SCAN_B + tid * 4;
    int v[4];
    int s = 0;
#pragma unroll
    for (int i = 0; i < 4; ++i) {
        v[i] = (base + i < n) ? cnt[base + i] : 0;
        s += v[i];
    }
    sm[tid] = s;
    __syncthreads();
    for (int off = 1; off < 256; off <<= 1) {
        int t = (tid >= off) ? sm[tid - off] : 0;
        __syncthreads();
        sm[tid] += t;
        __syncthreads();
    }
    int run = sm[tid] - s + blk_off[blockIdx.x];
#pragma unroll
    for (int i = 0; i < 4; ++i) {
        if (base + i < n) {
            row_start[base + i] = run;
            cursor[base + i] = run;
        }
        run += v[i];
    }
}

// --- bucketed scatter: bucket = blockIdx&7 (XCD round-robin heuristic) ---
// dst: regular load (L3-served, re-read 8x). src/u: nt loads (single-use) so
// the bucket's ~1.6 MB em write window keeps L2 residency and lines fill.
__global__ __launch_bounds__(256) void k_scatter(const int* __restrict__ src,
                                                 const int* __restrict__ dst,
                                                 const float* __restrict__ u,
                                                 int* __restrict__ cursor,
                                                 int2* __restrict__ em,
                                                 int n_edges, int nodes_per_bucket) {
    int bucket = blockIdx.x & 7;
    int chunk = blockIdx.x >> 3;
    int nchunks = gridDim.x >> 3;
    int per = (n_edges + nchunks - 1) / nchunks;
    int e0 = chunk * per;
    int e1 = min(e0 + per, n_edges);
    int lo = bucket * nodes_per_bucket;
    int hi = lo + nodes_per_bucket;
    for (int e = e0 + threadIdx.x; e < e1; e += 256) {
        int d = dst[e];
        if (d >= lo && d < hi) {
            int s = __builtin_nontemporal_load(src + e);
            float uu = __builtin_nontemporal_load(u + e);
            int p = atomicAdd(&cursor[d], 1);
            em[p] = make_int2(s, __float_as_int(uu));
        }
    }
}

// --- aggregate: one wave per node, lane = channel; packed bf16 h01 ---
// em via nt loads (single-use within this kernel, keeps L2 for h01 reuse).
// Tail handled as one masked 8-wide iteration (no serialized scalar tail).
__global__ __launch_bounds__(256) void k_agg(const unsigned* __restrict__ h01,
                                             const long long* __restrict__ em,
                                             const int* __restrict__ row_start,
                                             const float* __restrict__ lin,
                                             float* __restrict__ out, int n_nodes) {
    int wave = threadIdx.x >> 6;
    int lane = threadIdx.x & 63;
    int n = blockIdx.x * 4 + wave;
    if (n >= n_nodes) return;
    int start = row_start[n];
    int end = row_start[n + 1];
    float acc = 0.0f;
    int j = start;
    for (; j + 8 <= end; j += 8) {
        long long e[8];
        unsigned v[8];
#pragma unroll
        for (int i = 0; i < 8; ++i) e[i] = __builtin_nontemporal_load(em + j + i);
#pragma unroll
        for (int i = 0; i < 8; ++i) {
            int s = (int)(e[i] & 0xffffffffLL);
            v[i] = h01[(size_t)s * CDIM + lane];
        }
#pragma unroll
        for (int i = 0; i < 8; ++i) {
            float a = __uint_as_float(v[i] << 16);
            float b = __uint_as_float(v[i] & 0xffff0000u);
            float uu = __int_as_float((int)(e[i] >> 32));
            acc += a + uu * (b - a);   // (1-u)h0 + u h1
        }
    }
    if (j < end) {                      // masked final iteration (1..7 edges)
        long long e[8];
        unsigned v[8];
        float msk[8];
#pragma unroll
        for (int i = 0; i < 8; ++i) {
            int jj = j + i;
            bool ok = jj < end;
            e[i] = __builtin_nontemporal_load(em + (ok ? jj : end - 1));
            msk[i] = ok ? 1.0f : 0.0f;
        }
#pragma unroll
        for (int i = 0; i < 8; ++i) {
            int s = (int)(e[i] & 0xffffffffLL);
            v[i] = h01[(size_t)s * CDIM + lane];
        }
#pragma unroll
        for (int i = 0; i < 8; ++i) {
            float a = __uint_as_float(v[i] << 16);
            float b = __uint_as_float(v[i] & 0xffff0000u);
            float uu = __int_as_float((int)(e[i] >> 32));
            acc += msk[i] * (a + uu * (b - a));
        }
    }
    float d = fmaxf((float)(end - start), 1.0f);
    size_t o = (size_t)n * CDIM + lane;
    out[o] = acc / d + lin[o];
}

extern "C" void kernel_launch(void* const* d_in, const int* in_sizes, int n_in,
                              void* d_out, int out_size, void* d_ws, size_t ws_size,
                              hipStream_t stream) {
    const float* x = (const float*)d_in[0];
    const int* edge_index = (const int*)d_in[1];
    const float* edge_attr = (const float*)d_in[2];
    const float* w1 = (const float*)d_in[3];
    const float* root1 = (const float*)d_in[4];
    const float* b1 = (const float*)d_in[5];
    const float* w2 = (const float*)d_in[6];
    const float* root2 = (const float*)d_in[7];
    const float* b2 = (const float*)d_in[8];

    int n_nodes = in_sizes[0] / CDIM;
    int n_edges = in_sizes[2];
    const int* src = edge_index;
    const int* dst = edge_index + n_edges;

    size_t F = (size_t)n_nodes * CDIM;
    unsigned* h01 = (unsigned*)d_ws;            // F u32 (bf16 pair)
    float* lin = (float*)(h01 + F);             // F floats
    int2* em = (int2*)(lin + F);                // E int2 (src, u)
    int* cnt = (int*)(em + n_edges);
    int* row_start = cnt + n_nodes;             // n+1
    int* cursor = row_start + n_nodes + 1;
    int* blk_sum = cursor + n_nodes;
    float* out = (float*)d_out;

    int gB = (n_nodes + 63) / 64;               // 64 nodes per gemm block
    int gE = (n_edges + 255) / 256;
    int gA = (n_nodes + 3) / 4;
    int nb = (n_nodes + SCAN_B - 1) / SCAN_B;   // 98 for 100k, fits k_scan2's 256
    int npb = (n_nodes + 7) / 8;                // nodes per scatter bucket

    // ---- build dst-CSR (shared by both layers) ----
    k_zero<<<256, 256, 0, stream>>>(cnt, (size_t)n_nodes);
    k_hist<<<gE, 256, 0, stream>>>(dst, cnt, n_edges);
    k_scan1<<<nb, 256, 0, stream>>>(cnt, blk_sum, n_nodes);
    k_scan2<<<1, 256, 0, stream>>>(blk_sum, row_start, nb, n_nodes);
    k_scan3<<<nb, 256, 0, stream>>>(cnt, blk_sum, row_start, cursor, n_nodes);
    k_scatter<<<8 * 128, 256, 0, stream>>>(src, dst, edge_attr, cursor, em, n_edges, npb);

    // ---- layer 1 ----
    k_gemm3<<<gB, 256, 0, stream>>>(x, w1, w1 + CDIM * CDIM, root1, b1, h01, lin, n_nodes);
    k_agg<<<gA, 256, 0, stream>>>(h01, (const long long*)em, row_start, lin, lin, n_nodes);

    // ---- layer 2 ----
    k_gemm3<<<gB, 256, 0, stream>>>(lin, w2, w2 + CDIM * CDIM, root2, b2, h01, out, n_nodes);
    k_agg<<<gA, 256, 0, stream>>>(h01, (const long long*)em, row_start, out, out, n_nodes);
}

// Round 9
// 402.432 us; speedup vs baseline: 1.2113x; 1.1271x over previous
//
#include <hip/hip_runtime.h>

#define CDIM 64

typedef __attribute__((ext_vector_type(8))) short bf16x8;
typedef __attribute__((ext_vector_type(4))) float f32x4;

// round-to-nearest-even fp32 -> bf16 (as short)
__device__ __forceinline__ short bf16r(float f) {
    unsigned a = __float_as_uint(f);
    a = (a + 0x7fffu + ((a >> 16) & 1u)) >> 16;
    return (short)a;
}
// pack two fp32 as bf16 pair: first -> bits[15:0], second -> bits[31:16]
__device__ __forceinline__ unsigned bfpack(float lo, float hi) {
    unsigned a = __float_as_uint(lo);
    a = (a + 0x7fffu + ((a >> 16) & 1u)) >> 16;
    unsigned b = __float_as_uint(hi);
    b = (b + 0x7fffu + ((b >> 16) & 1u)) & 0xffff0000u;
    return a | b;
}

// --- pack x (fp32) -> bf16 pairs (u32 per 2 channels) ---
__global__ __launch_bounds__(256) void k_pack(const float* __restrict__ x,
                                              unsigned* __restrict__ xb32, size_t n2) {
    size_t t = (size_t)blockIdx.x * 256 + threadIdx.x;
    size_t stride = (size_t)gridDim.x * 256;
    for (size_t i = t; i < n2; i += stride) {
        float2 v = ((const float2*)x)[i];
        xb32[i] = bfpack(v.x, v.y);
    }
}

// --- zero-fill ---
__global__ __launch_bounds__(256) void k_zero(int* __restrict__ p, size_t n) {
    size_t t = (size_t)blockIdx.x * 256 + threadIdx.x;
    size_t stride = (size_t)gridDim.x * 256;
    for (size_t i = t; i < n; i += stride) p[i] = 0;
}

// --- histogram of dst (regular loads: dst is re-read 8x by scatter, keep cached) ---
__global__ __launch_bounds__(256) void k_hist(const int* __restrict__ dst,
                                              int* __restrict__ cnt, int n_edges) {
    int e = blockIdx.x * 256 + threadIdx.x;
    if (e >= n_edges) return;
    atomicAdd(&cnt[dst[e]], 1);
}

// ===== two-level scan: 1024 elements per block =====
#define SCAN_B 1024

__global__ __launch_bounds__(256) void k_scan1(const int* __restrict__ cnt,
                                               int* __restrict__ blk_sum, int n) {
    __shared__ int sm[256];
    int tid = threadIdx.x;
    int base = blockIdx.x * SCAN_B + tid * 4;
    int s = 0;
#pragma unroll
    for (int i = 0; i < 4; ++i) s += (base + i < n) ? cnt[base + i] : 0;
    sm[tid] = s;
    __syncthreads();
    for (int off = 128; off > 0; off >>= 1) {
        if (tid < off) sm[tid] += sm[tid + off];
        __syncthreads();
    }
    if (tid == 0) blk_sum[blockIdx.x] = sm[0];
}

__global__ __launch_bounds__(256) void k_scan2(int* __restrict__ blk_sum,
                                               int* __restrict__ row_start,
                                               int nb, int n) {
    __shared__ int sm[256];
    int tid = threadIdx.x;
    int v = (tid < nb) ? blk_sum[tid] : 0;
    sm[tid] = v;
    __syncthreads();
    for (int off = 1; off < 256; off <<= 1) {
        int t = (tid >= off) ? sm[tid - off] : 0;
        __syncthreads();
        sm[tid] += t;
        __syncthreads();
    }
    if (tid < nb) blk_sum[tid] = sm[tid] - v;  // exclusive
    if (tid == 255) row_start[n] = sm[255];    // grand total
}

__global__ __launch_bounds__(256) void k_scan3(const int* __restrict__ cnt,
                                               const int* __restrict__ blk_off,
                                               int* __restrict__ row_start,
                                               int* __restrict__ cursor, int n) {
    __shared__ int sm[256];
    int tid = threadIdx.x;
    int base = blockIdx.x * SCAN_B + tid * 4;
    int v[4];
    int s = 0;
#pragma unroll
    for (int i = 0; i < 4; ++i) {
        v[i] = (base + i < n) ? cnt[base + i] : 0;
        s += v[i];
    }
    sm[tid] = s;
    __syncthreads();
    for (int off = 1; off < 256; off <<= 1) {
        int t = (tid >= off) ? sm[tid - off] : 0;
        __syncthreads();
        sm[tid] += t;
        __syncthreads();
    }
    int run = sm[tid] - s + blk_off[blockIdx.x];
#pragma unroll
    for (int i = 0; i < 4; ++i) {
        if (base + i < n) {
            row_start[base + i] = run;
            cursor[base + i] = run;
        }
        run += v[i];
    }
}

// --- bucketed scatter: em32 = (src << 15) | round(u*32767); 4 B/edge payload ---
__global__ __launch_bounds__(256) void k_scatter(const int* __restrict__ src,
                                                 const int* __restrict__ dst,
                                                 const float* __restrict__ u,
                                                 int* __restrict__ cursor,
                                                 unsigned* __restrict__ em32,
                                                 int n_edges, int nodes_per_bucket) {
    int bucket = blockIdx.x & 7;
    int chunk = blockIdx.x >> 3;
    int nchunks = gridDim.x >> 3;
    int per = (n_edges + nchunks - 1) / nchunks;
    int e0 = chunk * per;
    int e1 = min(e0 + per, n_edges);
    int lo = bucket * nodes_per_bucket;
    int hi = lo + nodes_per_bucket;
    for (int e = e0 + threadIdx.x; e < e1; e += 256) {
        int d = dst[e];
        if (d >= lo && d < hi) {
            int s = __builtin_nontemporal_load(src + e);          // true single-use
            float uu = __builtin_nontemporal_load(u + e);         // true single-use
            unsigned uq = (unsigned)(uu * 32767.0f + 0.5f);
            int p = atomicAdd(&cursor[d], 1);
            em32[p] = ((unsigned)s << 15) | uq;
        }
    }
}

// --- aggregate raw x: wave per node; half-wave per edge, 2 channels/lane ---
// g[n][0..63] = sum (1-u) x[src], g[n][64..127] = sum u x[src]; both / max(deg,1)
__global__ __launch_bounds__(256) void k_aggx(const unsigned* __restrict__ xb32,
                                              const unsigned* __restrict__ em32,
                                              const int* __restrict__ row_start,
                                              float* __restrict__ g, int n_nodes) {
    int wave = threadIdx.x >> 6;
    int lane = threadIdx.x & 63;
    int half = lane >> 5;        // edge parity handled by this half-wave
    int hl = lane & 31;          // channel-pair index (channels 2hl, 2hl+1)
    int n = blockIdx.x * 4 + wave;
    if (n >= n_nodes) return;
    int start = row_start[n];
    int end = row_start[n + 1];
    const float inv15 = 1.0f / 32767.0f;
    float g0a = 0.f, g0b = 0.f, g1a = 0.f, g1b = 0.f;
    int j = start;
    for (; j + 8 <= end; j += 8) {
        unsigned e[4], v[4];
#pragma unroll
        for (int i = 0; i < 4; ++i) e[i] = em32[j + 2 * i + half];
#pragma unroll
        for (int i = 0; i < 4; ++i) v[i] = xb32[(size_t)(e[i] >> 15) * 32 + hl];
#pragma unroll
        for (int i = 0; i < 4; ++i) {
            float uu = (float)(e[i] & 0x7fffu) * inv15;
            float c0 = __uint_as_float(v[i] << 16);
            float c1 = __uint_as_float(v[i] & 0xffff0000u);
            float wa = 1.0f - uu;
            g0a += wa * c0; g0b += wa * c1;
            g1a += uu * c0; g1b += uu * c1;
        }
    }
    if (j < end) {   // masked final group (1..7 edges)
        unsigned e[4], v[4];
        float m[4];
#pragma unroll
        for (int i = 0; i < 4; ++i) {
            int idx = j + 2 * i + half;
            bool ok = idx < end;
            e[i] = em32[ok ? idx : (end - 1)];
            m[i] = ok ? 1.0f : 0.0f;
        }
#pragma unroll
        for (int i = 0; i < 4; ++i) v[i] = xb32[(size_t)(e[i] >> 15) * 32 + hl];
#pragma unroll
        for (int i = 0; i < 4; ++i) {
            float uu = (float)(e[i] & 0x7fffu) * inv15;
            float c0 = __uint_as_float(v[i] << 16);
            float c1 = __uint_as_float(v[i] & 0xffff0000u);
            float wa = (1.0f - uu) * m[i], wb = uu * m[i];
            g0a += wa * c0; g0b += wa * c1;
            g1a += wb * c0; g1b += wb * c1;
        }
    }
    // combine the two edge-parity halves
    g0a += __shfl_xor(g0a, 32);
    g0b += __shfl_xor(g0b, 32);
    g1a += __shfl_xor(g1a, 32);
    g1b += __shfl_xor(g1b, 32);
    float s = 1.0f / fmaxf((float)(end - start), 1.0f);
    if (half == 0) {
        float2* gp = (float2*)(g + (size_t)n * 128);
        gp[hl] = make_float2(g0a * s, g0b * s);
        gp[32 + hl] = make_float2(g1a * s, g1b * s);
    }
}

// --- K=192 MFMA GEMM: out = g0@w0 + g1@w1 + xr@root + bias; also pack bf16 next-x ---
// m92-verified layout: A[m=lane&15][k=quad*8+j]; B from Wt[n=lane&15][k]; D col=m16, row=quad*4+r.
__global__ __launch_bounds__(256) void k_gemm(const float* __restrict__ g,
                                              const float* __restrict__ xr,
                                              const float* __restrict__ w0,
                                              const float* __restrict__ w1,
                                              const float* __restrict__ root,
                                              const float* __restrict__ bias,
                                              float* __restrict__ out,
                                              unsigned short* __restrict__ xb_next,
                                              int n_nodes) {
    __shared__ __align__(16) short wt[3][64][72];  // k padded 64->72 (144 B rows)
    const float* ws[3] = {w0, w1, root};
#pragma unroll
    for (int m = 0; m < 3; ++m) {
        const float* w = ws[m];
        for (int i = threadIdx.x; i < 4096; i += 256) {
            int k = i >> 6, n = i & 63;   // w row-major [k][n]
            wt[m][n][k] = bf16r(w[i]);
        }
    }
    __syncthreads();

    int wave = threadIdx.x >> 6;
    int lane = threadIdx.x & 63;
    int quad = lane >> 4;
    int m16 = lane & 15;
    int node0 = blockIdx.x * 64 + wave * 16;
    int arow = node0 + m16;
    bool rowok = arow < n_nodes;

    bf16x8 aG0[2], aG1[2], aX[2];
    const float* g0p = g + (size_t)arow * 128 + quad * 8;
    const float* g1p = g0p + 64;
    const float* xp = xr + (size_t)arow * CDIM + quad * 8;
#pragma unroll
    for (int kf = 0; kf < 2; ++kf) {
        float4 l0 = {0,0,0,0}, h0 = {0,0,0,0};
        float4 l1 = {0,0,0,0}, h1 = {0,0,0,0};
        float4 lx = {0,0,0,0}, hx = {0,0,0,0};
        if (rowok) {
            l0 = *(const float4*)(g0p + kf * 32); h0 = *(const float4*)(g0p + kf * 32 + 4);
            l1 = *(const float4*)(g1p + kf * 32); h1 = *(const float4*)(g1p + kf * 32 + 4);
            lx = *(const float4*)(xp + kf * 32);  hx = *(const float4*)(xp + kf * 32 + 4);
        }
        bf16x8 a, b, c;
        a[0]=bf16r(l0.x); a[1]=bf16r(l0.y); a[2]=bf16r(l0.z); a[3]=bf16r(l0.w);
        a[4]=bf16r(h0.x); a[5]=bf16r(h0.y); a[6]=bf16r(h0.z); a[7]=bf16r(h0.w);
        b[0]=bf16r(l1.x); b[1]=bf16r(l1.y); b[2]=bf16r(l1.z); b[3]=bf16r(l1.w);
        b[4]=bf16r(h1.x); b[5]=bf16r(h1.y); b[6]=bf16r(h1.z); b[7]=bf16r(h1.w);
        c[0]=bf16r(lx.x); c[1]=bf16r(lx.y); c[2]=bf16r(lx.z); c[3]=bf16r(lx.w);
        c[4]=bf16r(hx.x); c[5]=bf16r(hx.y); c[6]=bf16r(hx.z); c[7]=bf16r(hx.w);
        aG0[kf] = a; aG1[kf] = b; aX[kf] = c;
    }

#pragma unroll
    for (int nt = 0; nt < 4; ++nt) {
        f32x4 acc = {0.f, 0.f, 0.f, 0.f};
#pragma unroll
        for (int kf = 0; kf < 2; ++kf) {
            bf16x8 b0 = *(const bf16x8*)&wt[0][nt * 16 + m16][kf * 32 + quad * 8];
            bf16x8 b1 = *(const bf16x8*)&wt[1][nt * 16 + m16][kf * 32 + quad * 8];
            bf16x8 bR = *(const bf16x8*)&wt[2][nt * 16 + m16][kf * 32 + quad * 8];
            acc = __builtin_amdgcn_mfma_f32_16x16x32_bf16(aG0[kf], b0, acc, 0, 0, 0);
            acc = __builtin_amdgcn_mfma_f32_16x16x32_bf16(aG1[kf], b1, acc, 0, 0, 0);
            acc = __builtin_amdgcn_mfma_f32_16x16x32_bf16(aX[kf], bR, acc, 0, 0, 0);
        }
        float bcol = bias[nt * 16 + m16];
#pragma unroll
        for (int r = 0; r < 4; ++r) {
            int node = node0 + quad * 4 + r;
            if (node < n_nodes) {
                size_t off = (size_t)node * CDIM + nt * 16 + m16;
                float o = acc[r] + bcol;
                out[off] = o;
                xb_next[off] = (unsigned short)bf16r(o);
            }
        }
    }
}

extern "C" void kernel_launch(void* const* d_in, const int* in_sizes, int n_in,
                              void* d_out, int out_size, void* d_ws, size_t ws_size,
                              hipStream_t stream) {
    const float* x = (const float*)d_in[0];
    const int* edge_index = (const int*)d_in[1];
    const float* edge_attr = (const float*)d_in[2];
    const float* w1 = (const float*)d_in[3];
    const float* root1 = (const float*)d_in[4];
    const float* b1 = (const float*)d_in[5];
    const float* w2 = (const float*)d_in[6];
    const float* root2 = (const float*)d_in[7];
    const float* b2 = (const float*)d_in[8];

    int n_nodes = in_sizes[0] / CDIM;
    int n_edges = in_sizes[2];
    const int* src = edge_index;
    const int* dst = edge_index + n_edges;

    size_t F = (size_t)n_nodes * CDIM;
    unsigned* xb32 = (unsigned*)d_ws;             // F/2 u32 (bf16 pairs)
    float* g = (float*)(xb32 + F / 2);            // 2F floats (g0|g1 per node)
    float* lin = g + 2 * F;                       // F floats (layer-1 output)
    unsigned* em32 = (unsigned*)(lin + F);        // E u32 (src<<15 | u15)
    int* cnt = (int*)(em32 + n_edges);
    int* row_start = cnt + n_nodes;               // n+1
    int* cursor = row_start + n_nodes + 1;
    int* blk_sum = cursor + n_nodes;
    float* out = (float*)d_out;

    int gB = (n_nodes + 63) / 64;                 // 64 nodes per gemm block
    int gE = (n_edges + 255) / 256;
    int gA = (n_nodes + 3) / 4;
    int nb = (n_nodes + SCAN_B - 1) / SCAN_B;     // 98 for 100k, fits k_scan2's 256
    int npb = (n_nodes + 7) / 8;                  // nodes per scatter bucket

    // ---- build dst-CSR + pack x (shared by both layers) ----
    k_pack<<<2048, 256, 0, stream>>>(x, xb32, F / 2);
    k_zero<<<256, 256, 0, stream>>>(cnt, (size_t)n_nodes);
    k_hist<<<gE, 256, 0, stream>>>(dst, cnt, n_edges);
    k_scan1<<<nb, 256, 0, stream>>>(cnt, blk_sum, n_nodes);
    k_scan2<<<1, 256, 0, stream>>>(blk_sum, row_start, nb, n_nodes);
    k_scan3<<<nb, 256, 0, stream>>>(cnt, blk_sum, row_start, cursor, n_nodes);
    k_scatter<<<8 * 128, 256, 0, stream>>>(src, dst, edge_attr, cursor, em32, n_edges, npb);

    // ---- layer 1 ----
    k_aggx<<<gA, 256, 0, stream>>>(xb32, em32, row_start, g, n_nodes);
    k_gemm<<<gB, 256, 0, stream>>>(g, x, w1, w1 + CDIM * CDIM, root1, b1,
                                   lin, (unsigned short*)xb32, n_nodes);

    // ---- layer 2 ----
    k_aggx<<<gA, 256, 0, stream>>>(xb32, em32, row_start, g, n_nodes);
    k_gemm<<<gB, 256, 0, stream>>>(g, lin, w2, w2 + CDIM * CDIM, root2, b2,
                                   out, (unsigned short*)xb32, n_nodes);
}